// Round 1
// baseline (1631.845 us; speedup 1.0000x reference)
//
#include <hip/hip_runtime.h>
#include <hip/hip_bf16.h>

typedef __bf16 bf16;
typedef __bf16 bf16x8 __attribute__((ext_vector_type(8)));
typedef float floatx4 __attribute__((ext_vector_type(4)));

#define MFMA16(a, b, c) __builtin_amdgcn_mfma_f32_16x16x32_bf16((a), (b), (c), 0, 0, 0)

static constexpr int Cn = 256, HWn = 65536, Wpix = 256;
static constexpr int NWIN = 8192;  // 8 * 32 * 32

// Swizzled element offsets. A "slot" is 16 B = 8 bf16. XOR the slot index with
// (row & 7) so that the standard tile-read pattern (rows = l15, slots = quad)
// spreads uniformly over all 8 bank-groups -> conflict-free ds_read_b128.
// Readers and writers MUST both go through these.
__device__ __forceinline__ int xoff(int row, int col) {  // 256-col tiles (xw / AO), 512 B rows
    return (row << 8) + ((((col >> 3) ^ (row & 7)) << 3) | (col & 7));
}
__device__ __forceinline__ int qoff(int row, int col) {  // 64-col tiles (Q/K/V/P), 128 B rows
    return (row << 6) + ((((col >> 3) ^ (row & 7)) << 3) | (col & 7));
}

__global__ void convert_weights_kernel(const float* __restrict__ qkv_w,
                                       const float* __restrict__ proj_w,
                                       bf16* __restrict__ qkv_wb,
                                       bf16* __restrict__ proj_wb) {
    int i = blockIdx.x * 256 + threadIdx.x;
    if (i < 768 * 256) qkv_wb[i] = (bf16)qkv_w[i];
    if (i < 256 * 256) proj_wb[i] = (bf16)proj_w[i];
}

// One block per 8x8 window. 16 waves. Fused: qkv-GEMM -> window attention -> proj.
__global__ __launch_bounds__(1024) void win_attn_kernel(
    const float* __restrict__ x,
    const float* __restrict__ qkv_b,
    const float* __restrict__ proj_b,
    const bf16* __restrict__ qkv_wb,   // [768][256] row-major bf16
    const bf16* __restrict__ proj_wb,  // [256][256] row-major bf16
    float* __restrict__ out)
{
    // Four 32 KB swizzled tiles (16384 bf16 each). Total LDS 128 KB.
    // bufA: xw[64][256] (phases 0-1)  then P[4][64][64] (phase 2)
    // bufB: Q[4][64][64] (n-major)    then AO[64][256]  (phases 3-4)
    // bufC: K[4][64][64] (m-major)
    // bufD: V[4][64][64] (d-major)
    __shared__ __align__(16) bf16 bufA[16384];
    __shared__ __align__(16) bf16 bufB[16384];
    __shared__ __align__(16) bf16 bufC[16384];
    __shared__ __align__(16) bf16 bufD[16384];

    // XCD swizzle: adjacent windows (same row) land on the same XCD for L2 locality
    int p = blockIdx.x;
    int wid = (p & 7) * (NWIN / 8) + (p >> 3);
    int b = wid >> 10;
    int rem = wid & 1023;
    int hn = rem >> 5, wn = rem & 31;
    int h0 = hn * 8, w0 = wn * 8;

    int tid = threadIdx.x;
    int wave = tid >> 6;
    int lane = tid & 63;
    int quad = lane >> 4;
    int l15 = lane & 15;

    // ---- Phase 0: load x window -> xw[t][c] bf16 (token t = r*8+k) ----
    {
        const float* xb = x + (size_t)b * Cn * HWn;
#pragma unroll
        for (int it = 0; it < 2; ++it) {
            int idx = tid + it * 1024;  // [0, 2048): (c, r)
            int c = idx >> 3, r = idx & 7;
            const float* g = xb + (size_t)c * HWn + (h0 + r) * Wpix + w0;
            float4 v0 = *(const float4*)g;
            float4 v1 = *(const float4*)(g + 4);
            float vals[8] = {v0.x, v0.y, v0.z, v0.w, v1.x, v1.y, v1.z, v1.w};
            int cs = c >> 3, cl = c & 7, rb8 = (r * 8) << 8;
            // row = r*8+k -> row&7 == k, so slot = cs ^ k (compile-time k per iter)
#pragma unroll
            for (int k = 0; k < 8; ++k)
                bufA[rb8 + (k << 8) + (((cs ^ k) << 3) | cl)] = (bf16)vals[k];
        }
    }
    __syncthreads();

    // ---- Phase 1: QKV GEMM. D[px][o] = sum_c xw[px][c] * qkv_w[o][c] + qkv_b[o] ----
    // wave handles o-tiles ot = wave*3 + j (j=0..2), all 4 px-tiles. 12 acc tiles/wave.
    {
        floatx4 acc[3][4];
#pragma unroll
        for (int j = 0; j < 3; ++j)
#pragma unroll
            for (int t = 0; t < 4; ++t) acc[j][t] = (floatx4){0.f, 0.f, 0.f, 0.f};
        int otbase = wave * 3;
#pragma unroll
        for (int c0 = 0; c0 < 256; c0 += 32) {
            // row&7 = l15&7 for all t -> swizzled slot is t-invariant
            int soff = ((((c0 >> 3) + quad) ^ (l15 & 7)) << 3);
            bf16x8 afr[4];
#pragma unroll
            for (int t = 0; t < 4; ++t)
                afr[t] = *(const bf16x8*)&bufA[((t * 16 + l15) << 8) + soff];
#pragma unroll
            for (int j = 0; j < 3; ++j) {
                int o = (otbase + j) * 16 + l15;
                bf16x8 bfr = *(const bf16x8*)&qkv_wb[o * 256 + c0 + quad * 8];
#pragma unroll
                for (int t = 0; t < 4; ++t)
                    acc[j][t] = MFMA16(afr[t], bfr, acc[j][t]);
            }
        }
        // Scatter to Q/K/V. Reference splits 768 channels HEAD-MAJOR:
        // head h = o/192; within-head j = o%192: Q=j<64, K=64..128, V=128..192.
#pragma unroll
        for (int j = 0; j < 3; ++j) {
            int ot = otbase + j;           // [0,48), 16 channels each; never straddles
            int hh = ot / 12;              // head
            int j12 = ot - hh * 12;
            int type = j12 >> 2;           // 0=Q, 1=K, 2=V
            int d = (j12 & 3) * 16 + l15;  // channel within head-part
            float bias = qkv_b[ot * 16 + l15];
            int hbase = hh * 4096;
#pragma unroll
            for (int t = 0; t < 4; ++t) {
#pragma unroll
                for (int r = 0; r < 4; ++r) {
                    int px = t * 16 + quad * 4 + r;
                    bf16 v = (bf16)(acc[j][t][r] + bias);
                    if (type == 0)      bufB[hbase + qoff(px, d)] = v;  // Q[n][d]
                    else if (type == 1) bufC[hbase + qoff(px, d)] = v;  // K[m][d]
                    else                bufD[hbase + qoff(d, px)] = v;  // V[d][m]
                }
            }
        }
    }
    __syncthreads();

    // ---- Phase 2: attention. wave -> (head, 16-row block) ----
    floatx4 oacc[4];
    {
        int hh = wave >> 2;
        int rb = wave & 3;
        int n0 = rb * 16;
        const bf16* Q = bufB + hh * 4096;
        const bf16* K = bufC + hh * 4096;
        const bf16* V = bufD + hh * 4096;
        bf16* P = bufA + hh * 4096;  // overlays xw (dead after phase 1 + barrier)

        floatx4 sacc[4];
#pragma unroll
        for (int mt = 0; mt < 4; ++mt) sacc[mt] = (floatx4){0.f, 0.f, 0.f, 0.f};
#pragma unroll
        for (int d0 = 0; d0 < 64; d0 += 32) {
            bf16x8 aq = *(const bf16x8*)&Q[qoff(n0 + l15, d0 + quad * 8)];
#pragma unroll
            for (int mt = 0; mt < 4; ++mt) {
                bf16x8 bk = *(const bf16x8*)&K[qoff(mt * 16 + l15, d0 + quad * 8)];
                sacc[mt] = MFMA16(aq, bk, sacc[mt]);
            }
        }
        // softmax (full 64 cols resident): rows n = n0 + quad*4 + r
        const float scale = 0.125f;  // dh^-0.5
#pragma unroll
        for (int r = 0; r < 4; ++r) {
            float m = -1e30f;
#pragma unroll
            for (int mt = 0; mt < 4; ++mt) m = fmaxf(m, sacc[mt][r]);
#pragma unroll
            for (int s = 1; s < 16; s <<= 1) m = fmaxf(m, __shfl_xor(m, s, 64));
            float sum = 0.f;
#pragma unroll
            for (int mt = 0; mt < 4; ++mt) {
                float e = __expf((sacc[mt][r] - m) * scale);
                sacc[mt][r] = e;
                sum += e;
            }
#pragma unroll
            for (int s = 1; s < 16; s <<= 1) sum += __shfl_xor(sum, s, 64);
            float rs = 1.0f / sum;
#pragma unroll
            for (int mt = 0; mt < 4; ++mt)
                P[qoff(n0 + quad * 4 + r, mt * 16 + l15)] = (bf16)(sacc[mt][r] * rs);
        }
        // O = P * V  (wave reads only its own P rows; same-wave RAW handled by lgkmcnt)
#pragma unroll
        for (int dt = 0; dt < 4; ++dt) oacc[dt] = (floatx4){0.f, 0.f, 0.f, 0.f};
#pragma unroll
        for (int m0 = 0; m0 < 64; m0 += 32) {
            bf16x8 ap = *(const bf16x8*)&P[qoff(n0 + l15, m0 + quad * 8)];
#pragma unroll
            for (int dt = 0; dt < 4; ++dt) {
                bf16x8 bv = *(const bf16x8*)&V[qoff(dt * 16 + l15, m0 + quad * 8)];
                oacc[dt] = MFMA16(ap, bv, oacc[dt]);
            }
        }
    }
    __syncthreads();  // all waves done reading Q -> bufB reusable as AO

    // ---- Phase 3: O -> AO[n][c], c = head*64 + d (head-major over C=256) ----
    {
        int hh = wave >> 2;
        int rb = wave & 3;
        int n0 = rb * 16;
#pragma unroll
        for (int dt = 0; dt < 4; ++dt)
#pragma unroll
            for (int r = 0; r < 4; ++r)
                bufB[xoff(n0 + quad * 4 + r, hh * 64 + dt * 16 + l15)] = (bf16)oacc[dt][r];
    }
    __syncthreads();

    // ---- Phase 4: proj. D[o2][px] = sum_c proj_w[o2][c] * AO[px][c] + proj_b ----
    {
        floatx4 pacc[4];
#pragma unroll
        for (int t = 0; t < 4; ++t) pacc[t] = (floatx4){0.f, 0.f, 0.f, 0.f};
        int o2base = wave * 16;
#pragma unroll
        for (int c0 = 0; c0 < 256; c0 += 32) {
            int soff = ((((c0 >> 3) + quad) ^ (l15 & 7)) << 3);
            bf16x8 aw = *(const bf16x8*)&proj_wb[(o2base + l15) * 256 + c0 + quad * 8];
#pragma unroll
            for (int t = 0; t < 4; ++t) {
                bf16x8 bb = *(const bf16x8*)&bufB[((t * 16 + l15) << 8) + soff];
                pacc[t] = MFMA16(aw, bb, pacc[t]);
            }
        }
        float* ob = out + (size_t)b * Cn * HWn;
#pragma unroll
        for (int t = 0; t < 4; ++t) {
#pragma unroll
            for (int r = 0; r < 4; ++r) {
                int o2 = o2base + quad * 4 + r;
                int px = t * 16 + l15;
                ob[(size_t)o2 * HWn + (h0 + (px >> 3)) * Wpix + w0 + (px & 7)] =
                    pacc[t][r] + proj_b[o2];
            }
        }
    }
}

extern "C" void kernel_launch(void* const* d_in, const int* in_sizes, int n_in,
                              void* d_out, int out_size, void* d_ws, size_t ws_size,
                              hipStream_t stream) {
    const float* x      = (const float*)d_in[0];
    const float* qkv_w  = (const float*)d_in[1];
    const float* qkv_b  = (const float*)d_in[2];
    const float* proj_w = (const float*)d_in[3];
    const float* proj_b = (const float*)d_in[4];
    float* out = (float*)d_out;

    bf16* qkv_wb  = (bf16*)d_ws;                 // 768*256 bf16
    bf16* proj_wb = qkv_wb + 768 * 256;          // 256*256 bf16

    convert_weights_kernel<<<768, 256, 0, stream>>>(qkv_w, proj_w, qkv_wb, proj_wb);
    win_attn_kernel<<<NWIN, 1024, 0, stream>>>(x, qkv_b, proj_b, qkv_wb, proj_wb, out);
}